// Round 1
// 206.590 us; speedup vs baseline: 1.0586x; 1.0586x over previous
//
#include <hip/hip_runtime.h>

typedef __bf16 bf16_t;
typedef __bf16 bf16x8 __attribute__((ext_vector_type(8)));
typedef float f32x4 __attribute__((ext_vector_type(4)));
typedef unsigned short u16x4 __attribute__((ext_vector_type(4)));

#define B_ 8
#define T_ 2048
#define C_ 1024
#define HS_ 64
#define VSTRIDE 2080  // vT row stride (T_+32): de-alias 4KB channel hotspot

#define MFMA __builtin_amdgcn_mfma_f32_16x16x32_bf16

__device__ __forceinline__ float fast_exp2(float x) {
#if __has_builtin(__builtin_amdgcn_exp2f)
  return __builtin_amdgcn_exp2f(x);
#else
  return exp2f(x);
#endif
}

// async 16B/lane global->LDS: per-lane gsrc, wave-uniform LDS base (+lane*16)
__device__ __forceinline__ void async_ld16(const void* gsrc, void* lds_dst) {
  __builtin_amdgcn_global_load_lds(
      (const __attribute__((address_space(1))) void*)gsrc,
      (__attribute__((address_space(3))) void*)lds_dst, 16, 0, 0);
}

// ---------------------------------------------------------------------------
// Kernel 1: repack W [1024][64] fp32 -> bf16 MFMA B-fragment order.
// Pack index: ((kc*4 + nt)*64 + lane)*8 + j  =  W[kc*32 + quad*8 + j][nt*16 + ln]
// ---------------------------------------------------------------------------
__global__ __launch_bounds__(256) void repack_w(
    const float* __restrict__ Wq, const float* __restrict__ Wk,
    const float* __restrict__ Wv, bf16_t* __restrict__ pq,
    bf16_t* __restrict__ pk, bf16_t* __restrict__ pv) {
  const float* W = (blockIdx.y == 0) ? Wq : ((blockIdx.y == 1) ? Wk : Wv);
  bf16_t* P = (blockIdx.y == 0) ? pq : ((blockIdx.y == 1) ? pk : pv);
  int t = blockIdx.x * 256 + threadIdx.x;  // 0..8191
  int lane = t & 63, nt = (t >> 6) & 3, kc = t >> 8;
  int quad = lane >> 4, ln = lane & 15;
  bf16x8 v;
#pragma unroll
  for (int j = 0; j < 8; ++j)
    v[j] = (bf16_t)W[(kc * 32 + quad * 8 + j) * HS_ + nt * 16 + ln];
  *(bf16x8*)(P + (size_t)t * 8) = v;
}

// ---------------------------------------------------------------------------
// Kernel 2: MFMA projections, fully pipelined staging (R8 redesign).
// R8 diagnosis: old loop drained vmcnt(0) per chunk AND interleaved B-frag
// global loads with staging; vmcnt retires IN ORDER, so every compiler wait
// on a B-load force-retired all older staging loads -> staging in-flight hit
// zero every chunk -> latency-serialized (HBM 13%, all pipes idle).
// Fix: the K-loop contains NO VMEM except staging. B-fragments (L2-resident,
// 16KB/chunk/matrix, already in fragment order) are staged to LDS linearly;
// A staged ping-pong in 128-col chunks with XOR(row&7) 16B-slot swizzle
// applied on BOTH the global source and the ds_read (rule: both-or-neither).
// Per chunk: compute -> lgkm(0) -> s_barrier -> STAGE(c+2) -> vmcnt(NV) ->
// s_barrier. Counted vmcnt(NV) == one chunk's loads => chunk c+1 landed,
// chunk c+2 stays in flight: per-wave in-flight never drops to zero.
// LDS 128KB (kv) -> 1 block/CU, 4 waves; BW-bound so in-flight bytes, not
// occupancy, is the resource that matters (Little: ~10KB/CU suffices; we
// hold 48-96KB). q and kv are separate instantiations (vmcnt literal 12/16).
// ---------------------------------------------------------------------------
template <bool KV>
__global__ __launch_bounds__(256) void proj_mfma(
    const float* __restrict__ x, const bf16_t* __restrict__ pA,
    const bf16_t* __restrict__ pB, bf16_t* __restrict__ outA,
    bf16_t* __restrict__ vT) {
  __shared__ float Xb[2][64][128];               // 64 KB ping-pong A (K=128)
  __shared__ bf16_t Bb[2][KV ? 2 : 1][16][512];  // 64/32 KB ping-pong B-frags

  const int w = threadIdx.x >> 6, lane = threadIdx.x & 63;
  const int quad = lane >> 4, ln = lane & 15;
  const int m0blk = blockIdx.x * 64;
  const int m0 = m0blk + w * 16;
  const int l32 = lane & 31, lhalf = lane >> 5;

  f32x4 acc0[4], acc1[4];
#pragma unroll
  for (int nt = 0; nt < 4; ++nt) {
    acc0[nt] = (f32x4){0.f, 0.f, 0.f, 0.f};
    acc1[nt] = (f32x4){0.f, 0.f, 0.f, 0.f};
  }

  // ---- stage chunk c into buffer buf: 8 A-instrs + 4(+4) B-instrs --------
  auto STAGE = [&](int c, int buf) {
#pragma unroll
    for (int i = 0; i < 8; ++i) {  // 2 rows per instr: lanes 0-31 / 32-63
      const int row = w * 16 + 2 * i + lhalf;
      const int sg = l32 ^ (row & 7);  // pre-swizzled global 16B slot
      async_ld16(x + (size_t)(m0blk + row) * C_ + c * 128 + sg * 4,
                 &Xb[buf][w * 16 + 2 * i][0]);
    }
#pragma unroll
    for (int j = 0; j < 4; ++j) {  // wave w stages frag pairs w*4..w*4+3
      const int p = w * 4 + j;
      async_ld16(pA + (size_t)(c * 16 + p) * 512 + lane * 8,
                 &Bb[buf][0][p][0]);
    }
    if constexpr (KV) {
#pragma unroll
      for (int j = 0; j < 4; ++j) {
        const int p = w * 4 + j;
        async_ld16(pB + (size_t)(c * 16 + p) * 512 + lane * 8,
                   &Bb[buf][1][p][0]);
      }
    }
  };

  // ---- compute chunk c from LDS only (vmcnt untouched) -------------------
  auto COMPUTE = [&](int c, int buf) {
    const int swz = (ln & 7) << 4;
    const char* rp = (const char*)&Xb[buf][w * 16 + ln][0];
#pragma unroll
    for (int kc2 = 0; kc2 < 4; ++kc2) {
      f32x4 xlo = *(const f32x4*)(rp + ((kc2 * 128 + quad * 32) ^ swz));
      f32x4 xhi = *(const f32x4*)(rp + ((kc2 * 128 + quad * 32 + 16) ^ swz));
      bf16x8 a;
#pragma unroll
      for (int j = 0; j < 4; ++j) {
        a[j] = (bf16_t)xlo[j];
        a[4 + j] = (bf16_t)xhi[j];
      }
#pragma unroll
      for (int nt = 0; nt < 4; ++nt) {
        bf16x8 b0 = *(const bf16x8*)&Bb[buf][0][kc2 * 4 + nt][lane * 8];
        acc0[nt] = MFMA(a, b0, acc0[nt], 0, 0, 0);
      }
      if constexpr (KV) {
#pragma unroll
        for (int nt = 0; nt < 4; ++nt) {
          bf16x8 b1 = *(const bf16x8*)&Bb[buf][1][kc2 * 4 + nt][lane * 8];
          acc1[nt] = MFMA(a, b1, acc1[nt], 0, 0, 0);
        }
      }
    }
  };

#define WAIT_CHUNK()                                        \
  do {                                                      \
    if constexpr (KV)                                       \
      asm volatile("s_waitcnt vmcnt(16)" ::: "memory");     \
    else                                                    \
      asm volatile("s_waitcnt vmcnt(12)" ::: "memory");     \
  } while (0)

  // prologue: chunks 0,1 in flight; wait only for chunk 0
  STAGE(0, 0);
  STAGE(1, 1);
  WAIT_CHUNK();
  __builtin_amdgcn_s_barrier();
  __builtin_amdgcn_sched_barrier(0);

#pragma unroll
  for (int c = 0; c < 8; ++c) {
    COMPUTE(c, c & 1);
    if (c == 7) break;
    asm volatile("s_waitcnt lgkmcnt(0)" ::: "memory");  // my reads done
    __builtin_amdgcn_s_barrier();                       // all reads of buf done
    __builtin_amdgcn_sched_barrier(0);
    if (c < 6) {
      STAGE(c + 2, c & 1);  // overwrite just-freed buffer
      WAIT_CHUNK();         // chunk c+1 landed; c+2 stays in flight
    } else {
      asm volatile("s_waitcnt vmcnt(0)" ::: "memory");  // drain chunk 7
    }
    __builtin_amdgcn_s_barrier();  // chunk c+1 visible to all waves
    __builtin_amdgcn_sched_barrier(0);
  }
#undef WAIT_CHUNK

  if constexpr (!KV) {
#pragma unroll
    for (int nt = 0; nt < 4; ++nt)
#pragma unroll
      for (int r = 0; r < 4; ++r)
        outA[(size_t)(m0 + quad * 4 + r) * HS_ + nt * 16 + ln] =
            (bf16_t)acc0[nt][r];
  } else {
#pragma unroll
    for (int nt = 0; nt < 4; ++nt)
#pragma unroll
      for (int r = 0; r < 4; ++r)
        outA[(size_t)(m0 + quad * 4 + r) * HS_ + nt * 16 + ln] =
            (bf16_t)acc0[nt][r];
    const int bb = m0 >> 11, t0 = m0 & (T_ - 1);
#pragma unroll
    for (int nt = 0; nt < 4; ++nt) {
      u16x4 pk4;
#pragma unroll
      for (int r = 0; r < 4; ++r) {
        bf16_t h = (bf16_t)acc1[nt][r];
        pk4[r] = *(unsigned short*)&h;
      }
      *(u16x4*)((unsigned short*)vT +
                ((size_t)(bb * HS_ + nt * 16 + ln)) * VSTRIDE + t0 + quad * 4) =
          pk4;
    }
  }
}

// ---------------------------------------------------------------------------
// Kernel 3: causal flash attention, KV-split x8, parallel epilogue.
// (unchanged this round)
// ---------------------------------------------------------------------------
__global__ __launch_bounds__(512) void attn_mfma(
    const bf16_t* __restrict__ q, const bf16_t* __restrict__ k,
    const bf16_t* __restrict__ vT, float* __restrict__ out) {
  __shared__ bf16_t p_lds[8][16][80];   // 20 KB: per-wave P transpose
  __shared__ float o_buf[8][16][66];    // 33 KB: all 8 waves' partial O
  __shared__ float l_buf[8][16][17];    //  8.7 KB: per-lane l partials

  const int b = blockIdx.x >> 7;
  const int gq = blockIdx.x & 127;      // 16-row q-group within batch
  const int w = threadIdx.x >> 6, lane = threadIdx.x & 63;
  const int quad = lane >> 4, ln = lane & 15;
  const int qr0 = gq * 16;
  const size_t bt = (size_t)b * T_;
  const int td = gq >> 2;               // diagonal 64-key tile index

  bf16x8 aq[2];
#pragma unroll
  for (int hc = 0; hc < 2; ++hc)
    aq[hc] = *(const bf16x8*)(q + (bt + qr0 + ln) * HS_ + hc * 32 + quad * 8);

  f32x4 o_acc[4];
  float l_part[4] = {0.f, 0.f, 0.f, 0.f};
#pragma unroll
  for (int nt = 0; nt < 4; ++nt) o_acc[nt] = (f32x4){0.f, 0.f, 0.f, 0.f};
  const float scl = 0.03125f * 1.44269504088896340736f;  // C^-0.5 * log2(e)

  for (int t = w; t <= td; t += 8) {
    const int kr0 = t * 64;

    // ---- S = Q K^T (16 q-rows x 64 keys) ----
    f32x4 s[4];
#pragma unroll
    for (int nt = 0; nt < 4; ++nt) s[nt] = (f32x4){0.f, 0.f, 0.f, 0.f};
#pragma unroll
    for (int hc = 0; hc < 2; ++hc)
#pragma unroll
      for (int nt = 0; nt < 4; ++nt) {
        bf16x8 bk = *(const bf16x8*)(k + (bt + kr0 + nt * 16 + ln) * HS_ +
                                     hc * 32 + quad * 8);
        s[nt] = MFMA(aq[hc], bk, s[nt], 0, 0, 0);
      }

    // ---- p = exp(s/32), mask diagonal tile, accumulate l, stage P ----
    const bool diag = (t == td);
#pragma unroll
    for (int nt = 0; nt < 4; ++nt)
#pragma unroll
      for (int r = 0; r < 4; ++r) {
        float e = fast_exp2(s[nt][r] * scl);
        if (diag && (kr0 + nt * 16 + ln > qr0 + quad * 4 + r)) e = 0.f;
        l_part[r] += e;
        p_lds[w][quad * 4 + r][nt * 16 + ln] = (bf16_t)e;
      }

    // ---- O += P V (per-wave LDS slice; same-wave DS ordering) ----
#pragma unroll
    for (int kc = 0; kc < 2; ++kc) {
      bf16x8 ap = *(const bf16x8*)&p_lds[w][ln][kc * 32 + quad * 8];
#pragma unroll
      for (int nt = 0; nt < 4; ++nt) {
        bf16x8 bv = *(const bf16x8*)(vT +
                                     ((size_t)(b * HS_ + nt * 16 + ln)) * VSTRIDE +
                                     kr0 + kc * 32 + quad * 8);
        o_acc[nt] = MFMA(ap, bv, o_acc[nt], 0, 0, 0);
      }
    }
  }

  // ---- all waves dump partials; combine split across waves ----
#pragma unroll
  for (int nt = 0; nt < 4; ++nt)
#pragma unroll
    for (int r = 0; r < 4; ++r)
      o_buf[w][quad * 4 + r][nt * 16 + ln] = o_acc[nt][r];
#pragma unroll
  for (int r = 0; r < 4; ++r) l_buf[w][quad * 4 + r][ln] = l_part[r];
  __syncthreads();

#pragma unroll
  for (int rr = 0; rr < 2; ++rr) {
    const int row = w + rr * 8;
    float o = 0.f, lsum = 0.f;
#pragma unroll
    for (int ww = 0; ww < 8; ++ww) {
      o += o_buf[ww][row][lane];
      lsum += l_buf[ww][row][lane & 15];
    }
#pragma unroll
    for (int off = 1; off < 16; off <<= 1) lsum += __shfl_xor(lsum, off);
    out[(bt + qr0 + row) * HS_ + lane] = o / lsum;
  }
}

// ---------------------------------------------------------------------------
extern "C" void kernel_launch(void* const* d_in, const int* in_sizes, int n_in,
                              void* d_out, int out_size, void* d_ws,
                              size_t ws_size, hipStream_t stream) {
  (void)in_sizes; (void)n_in; (void)out_size; (void)ws_size;
  const float* xq = (const float*)d_in[0];   // fp32 in / fp32 out: proven R4
  const float* xkv = (const float*)d_in[1];
  const float* Wq = (const float*)d_in[2];
  const float* Wk = (const float*)d_in[3];
  const float* Wv = (const float*)d_in[4];
  float* out = (float*)d_out;

  char* ws = (char*)d_ws;
  bf16_t* q = (bf16_t*)ws;                              // 2 MB   [B*T][64]
  bf16_t* kk = (bf16_t*)(ws + (2u << 20));              // 2 MB   [B*T][64]
  bf16_t* vT = (bf16_t*)(ws + (4u << 20));              // 2.04MB [B][64][VSTRIDE]
  bf16_t* pq = (bf16_t*)(ws + (6656u << 10));           // 128 KB packed W @6.5MB
  bf16_t* pk = (bf16_t*)(ws + (6784u << 10));
  bf16_t* pv = (bf16_t*)(ws + (6912u << 10));

  repack_w<<<dim3(32, 3), 256, 0, stream>>>(Wq, Wk, Wv, pq, pk, pv);
  proj_mfma<false><<<dim3(256), 256, 0, stream>>>(xq, pq, nullptr, q, nullptr);
  proj_mfma<true><<<dim3(256), 256, 0, stream>>>(xkv, pk, pv, kk, vT);
  attn_mfma<<<dim3(1024), 512, 0, stream>>>(q, kk, vT, out);
}

// Round 2
// 198.168 us; speedup vs baseline: 1.1036x; 1.0425x over previous
//
#include <hip/hip_runtime.h>

typedef __bf16 bf16_t;
typedef __bf16 bf16x8 __attribute__((ext_vector_type(8)));
typedef float f32x4 __attribute__((ext_vector_type(4)));
typedef unsigned short u16x4 __attribute__((ext_vector_type(4)));

#define B_ 8
#define T_ 2048
#define C_ 1024
#define HS_ 64
#define VSTRIDE 2080  // vT row stride (T_+32): de-alias 4KB channel hotspot

#define MFMA __builtin_amdgcn_mfma_f32_16x16x32_bf16

__device__ __forceinline__ float fast_exp2(float x) {
#if __has_builtin(__builtin_amdgcn_exp2f)
  return __builtin_amdgcn_exp2f(x);
#else
  return exp2f(x);
#endif
}

// async 16B/lane global->LDS: per-lane gsrc, wave-uniform LDS base (+lane*16)
__device__ __forceinline__ void async_ld16(const void* gsrc, void* lds_dst) {
  __builtin_amdgcn_global_load_lds(
      (const __attribute__((address_space(1))) void*)gsrc,
      (__attribute__((address_space(3))) void*)lds_dst, 16, 0, 0);
}

// ---------------------------------------------------------------------------
// Kernel 1: repack W [1024][64] fp32 -> bf16 MFMA B-fragment order.
// Pack index: ((kc*4 + nt)*64 + lane)*8 + j  =  W[kc*32 + quad*8 + j][nt*16 + ln]
// ---------------------------------------------------------------------------
__global__ __launch_bounds__(256) void repack_w(
    const float* __restrict__ Wq, const float* __restrict__ Wk,
    const float* __restrict__ Wv, bf16_t* __restrict__ pq,
    bf16_t* __restrict__ pk, bf16_t* __restrict__ pv) {
  const float* W = (blockIdx.y == 0) ? Wq : ((blockIdx.y == 1) ? Wk : Wv);
  bf16_t* P = (blockIdx.y == 0) ? pq : ((blockIdx.y == 1) ? pk : pv);
  int t = blockIdx.x * 256 + threadIdx.x;  // 0..8191
  int lane = t & 63, nt = (t >> 6) & 3, kc = t >> 8;
  int quad = lane >> 4, ln = lane & 15;
  bf16x8 v;
#pragma unroll
  for (int j = 0; j < 8; ++j)
    v[j] = (bf16_t)W[(kc * 32 + quad * 8 + j) * HS_ + nt * 16 + ln];
  *(bf16x8*)(P + (size_t)t * 8) = v;
}

// ---------------------------------------------------------------------------
// Kernel 2: MFMA projections, fully pipelined staging (R8/R9).
// R9: re-merged q/kv into ONE dispatch (grid (256,2), runtime-uniform is_kv)
// to remove the inter-dispatch drain: finished q-blocks immediately backfill
// with kv-blocks. Pipeline unchanged from R8: the K-loop contains NO VMEM
// except staging (B-fragments staged to LDS linearly; A staged ping-pong in
// 128-col chunks with XOR(row&7) 16B-slot swizzle on BOTH global source and
// ds_read). Per chunk: compute -> lgkm(0) -> s_barrier -> STAGE(c+2) ->
// vmcnt(one chunk: 12 q / 16 kv) -> s_barrier. Per-wave staging in-flight
// never drops to zero. LDS 128KB -> 1 block/CU, 4 waves; BW-bound regime
// needs in-flight bytes, not occupancy.
// ---------------------------------------------------------------------------
__global__ __launch_bounds__(256) void proj_mfma(
    const float* __restrict__ xq, const float* __restrict__ xkv,
    const bf16_t* __restrict__ pq, const bf16_t* __restrict__ pk,
    const bf16_t* __restrict__ pv, bf16_t* __restrict__ q,
    bf16_t* __restrict__ k, bf16_t* __restrict__ vT) {
  __shared__ float Xb[2][64][128];       // 64 KB ping-pong A (K=128)
  __shared__ bf16_t Bb[2][2][16][512];   // 64 KB ping-pong B-frags

  const bool is_kv = (blockIdx.y != 0);
  const float* x = is_kv ? xkv : xq;
  const bf16_t* pA = is_kv ? pk : pq;
  const bf16_t* pB = pv;  // only read when is_kv
  bf16_t* outA = is_kv ? k : q;

  const int w = threadIdx.x >> 6, lane = threadIdx.x & 63;
  const int quad = lane >> 4, ln = lane & 15;
  const int m0blk = blockIdx.x * 64;
  const int m0 = m0blk + w * 16;
  const int l32 = lane & 31, lhalf = lane >> 5;

  f32x4 acc0[4], acc1[4];
#pragma unroll
  for (int nt = 0; nt < 4; ++nt) {
    acc0[nt] = (f32x4){0.f, 0.f, 0.f, 0.f};
    acc1[nt] = (f32x4){0.f, 0.f, 0.f, 0.f};
  }

  // ---- stage chunk c into buffer buf: 8 A-instrs + 4(+4) B-instrs --------
  auto STAGE = [&](int c, int buf) {
#pragma unroll
    for (int i = 0; i < 8; ++i) {  // 2 rows per instr: lanes 0-31 / 32-63
      const int row = w * 16 + 2 * i + lhalf;
      const int sg = l32 ^ (row & 7);  // pre-swizzled global 16B slot
      async_ld16(x + (size_t)(m0blk + row) * C_ + c * 128 + sg * 4,
                 &Xb[buf][w * 16 + 2 * i][0]);
    }
#pragma unroll
    for (int j = 0; j < 4; ++j) {  // wave w stages frag pairs w*4..w*4+3
      const int p = w * 4 + j;
      async_ld16(pA + (size_t)(c * 16 + p) * 512 + lane * 8,
                 &Bb[buf][0][p][0]);
    }
    if (is_kv) {
#pragma unroll
      for (int j = 0; j < 4; ++j) {
        const int p = w * 4 + j;
        async_ld16(pB + (size_t)(c * 16 + p) * 512 + lane * 8,
                   &Bb[buf][1][p][0]);
      }
    }
  };

  // ---- compute chunk c from LDS only (vmcnt untouched) -------------------
  auto COMPUTE = [&](int buf) {
    const int swz = (ln & 7) << 4;
    const char* rp = (const char*)&Xb[buf][w * 16 + ln][0];
#pragma unroll
    for (int kc2 = 0; kc2 < 4; ++kc2) {
      f32x4 xlo = *(const f32x4*)(rp + ((kc2 * 128 + quad * 32) ^ swz));
      f32x4 xhi = *(const f32x4*)(rp + ((kc2 * 128 + quad * 32 + 16) ^ swz));
      bf16x8 a;
#pragma unroll
      for (int j = 0; j < 4; ++j) {
        a[j] = (bf16_t)xlo[j];
        a[4 + j] = (bf16_t)xhi[j];
      }
#pragma unroll
      for (int nt = 0; nt < 4; ++nt) {
        bf16x8 b0 = *(const bf16x8*)&Bb[buf][0][kc2 * 4 + nt][lane * 8];
        acc0[nt] = MFMA(a, b0, acc0[nt], 0, 0, 0);
      }
      if (is_kv) {
#pragma unroll
        for (int nt = 0; nt < 4; ++nt) {
          bf16x8 b1 = *(const bf16x8*)&Bb[buf][1][kc2 * 4 + nt][lane * 8];
          acc1[nt] = MFMA(a, b1, acc1[nt], 0, 0, 0);
        }
      }
    }
  };

#define WAIT_CHUNK()                                        \
  do {                                                      \
    if (is_kv)                                              \
      asm volatile("s_waitcnt vmcnt(16)" ::: "memory");     \
    else                                                    \
      asm volatile("s_waitcnt vmcnt(12)" ::: "memory");     \
  } while (0)

  // prologue: chunks 0,1 in flight; wait only for chunk 0
  STAGE(0, 0);
  STAGE(1, 1);
  WAIT_CHUNK();
  __builtin_amdgcn_s_barrier();
  __builtin_amdgcn_sched_barrier(0);

#pragma unroll
  for (int c = 0; c < 8; ++c) {
    COMPUTE(c & 1);
    if (c == 7) break;
    asm volatile("s_waitcnt lgkmcnt(0)" ::: "memory");  // my reads done
    __builtin_amdgcn_s_barrier();                       // all reads of buf done
    __builtin_amdgcn_sched_barrier(0);
    if (c < 6) {
      STAGE(c + 2, c & 1);  // overwrite just-freed buffer
      WAIT_CHUNK();         // chunk c+1 landed; c+2 stays in flight
    } else {
      asm volatile("s_waitcnt vmcnt(0)" ::: "memory");  // drain chunk 7
    }
    __builtin_amdgcn_s_barrier();  // chunk c+1 visible to all waves
    __builtin_amdgcn_sched_barrier(0);
  }
#undef WAIT_CHUNK

#pragma unroll
  for (int nt = 0; nt < 4; ++nt)
#pragma unroll
    for (int r = 0; r < 4; ++r)
      outA[(size_t)(m0 + quad * 4 + r) * HS_ + nt * 16 + ln] =
          (bf16_t)acc0[nt][r];
  if (is_kv) {
    const int bb = m0 >> 11, t0 = m0 & (T_ - 1);
#pragma unroll
    for (int nt = 0; nt < 4; ++nt) {
      u16x4 pk4;
#pragma unroll
      for (int r = 0; r < 4; ++r) {
        bf16_t h = (bf16_t)acc1[nt][r];
        pk4[r] = *(unsigned short*)&h;
      }
      *(u16x4*)((unsigned short*)vT +
                ((size_t)(bb * HS_ + nt * 16 + ln)) * VSTRIDE + t0 + quad * 4) =
          pk4;
    }
  }
}

// ---------------------------------------------------------------------------
// Kernel 3: causal flash attention, KV-split x8, parallel epilogue.
// R9: (a) software pipeline — V-frag loads issued at tile start (independent
// of S), next tile's K-frags prefetched right after the S-MFMAs consume the
// current ones; vmcnt is in-order and issue order bk_i..bv_i..bk_{i+1} means
// waiting on bv_i never drains bk_{i+1}: both L2 round trips leave the
// per-tile critical path. (b) batch->XCD affinity (bid&7 == b -> each
// batch's k/vT/q L2-resident on one XCD) + heavy-first launch (gq = 127 -
// bid>>3) so the tail runs light blocks. __launch_bounds__(512,4) caps VGPR
// at 128 to keep 2 blocks/CU with bk[8]+bv[8] held.
// Fixed softmax max (|s| <~ 1.5): p = exp2(s*scl), l deferred; partials
// combine by ADDITION through LDS; scale = C^-0.5 = 1/32.
// ---------------------------------------------------------------------------
__global__ __launch_bounds__(512, 4) void attn_mfma(
    const bf16_t* __restrict__ q, const bf16_t* __restrict__ k,
    const bf16_t* __restrict__ vT, float* __restrict__ out) {
  __shared__ bf16_t p_lds[8][16][80];   // 20 KB: per-wave P transpose
  __shared__ float o_buf[8][16][66];    // 33 KB: all 8 waves' partial O
  __shared__ float l_buf[8][16][17];    //  8.7 KB: per-lane l partials

  const int b = blockIdx.x & 7;            // batch == XCD (round-robin %8)
  const int gq = 127 - (blockIdx.x >> 3);  // heavy q-groups launch first
  const int w = threadIdx.x >> 6, lane = threadIdx.x & 63;
  const int quad = lane >> 4, ln = lane & 15;
  const int qr0 = gq * 16;
  const size_t bt = (size_t)b * T_;
  const int td = gq >> 2;               // diagonal 64-key tile index

  bf16x8 aq[2];
#pragma unroll
  for (int hc = 0; hc < 2; ++hc)
    aq[hc] = *(const bf16x8*)(q + (bt + qr0 + ln) * HS_ + hc * 32 + quad * 8);

  f32x4 o_acc[4];
  float l_part[4] = {0.f, 0.f, 0.f, 0.f};
#pragma unroll
  for (int nt = 0; nt < 4; ++nt) o_acc[nt] = (f32x4){0.f, 0.f, 0.f, 0.f};
  const float scl = 0.03125f * 1.44269504088896340736f;  // C^-0.5 * log2(e)

  bf16x8 bk[8], bv[8];
  int t = w;
  if (t <= td) {  // prologue K-frag load for first tile
#pragma unroll
    for (int hc = 0; hc < 2; ++hc)
#pragma unroll
      for (int nt = 0; nt < 4; ++nt)
        bk[hc * 4 + nt] = *(const bf16x8*)(k + (bt + t * 64 + nt * 16 + ln) * HS_ +
                                           hc * 32 + quad * 8);
  }

  for (; t <= td; t += 8) {
    const int kr0 = t * 64;

    // ---- V-frag loads for THIS tile: independent of S, issue first ----
#pragma unroll
    for (int kc = 0; kc < 2; ++kc)
#pragma unroll
      for (int nt = 0; nt < 4; ++nt)
        bv[kc * 4 + nt] = *(const bf16x8*)(vT +
                                           ((size_t)(b * HS_ + nt * 16 + ln)) * VSTRIDE +
                                           kr0 + kc * 32 + quad * 8);

    // ---- S = Q K^T (16 q-rows x 64 keys), consumes bk ----
    f32x4 s[4];
#pragma unroll
    for (int nt = 0; nt < 4; ++nt) s[nt] = (f32x4){0.f, 0.f, 0.f, 0.f};
#pragma unroll
    for (int hc = 0; hc < 2; ++hc)
#pragma unroll
      for (int nt = 0; nt < 4; ++nt)
        s[nt] = MFMA(aq[hc], bk[hc * 4 + nt], s[nt], 0, 0, 0);

    // ---- prefetch next tile's K-frags (bk free after S-MFMA issue) ----
    if (t + 8 <= td) {
#pragma unroll
      for (int hc = 0; hc < 2; ++hc)
#pragma unroll
        for (int nt = 0; nt < 4; ++nt)
          bk[hc * 4 + nt] = *(const bf16x8*)(k +
                                             (bt + (t + 8) * 64 + nt * 16 + ln) * HS_ +
                                             hc * 32 + quad * 8);
    }

    // ---- p = exp(s/32), mask diagonal tile, accumulate l, stage P ----
    const bool diag = (t == td);
#pragma unroll
    for (int nt = 0; nt < 4; ++nt)
#pragma unroll
      for (int r = 0; r < 4; ++r) {
        float e = fast_exp2(s[nt][r] * scl);
        if (diag && (kr0 + nt * 16 + ln > qr0 + quad * 4 + r)) e = 0.f;
        l_part[r] += e;
        p_lds[w][quad * 4 + r][nt * 16 + ln] = (bf16_t)e;
      }

    // ---- O += P V (per-wave LDS slice; same-wave DS ordering) ----
#pragma unroll
    for (int kc = 0; kc < 2; ++kc) {
      bf16x8 ap = *(const bf16x8*)&p_lds[w][ln][kc * 32 + quad * 8];
#pragma unroll
      for (int nt = 0; nt < 4; ++nt)
        o_acc[nt] = MFMA(ap, bv[kc * 4 + nt], o_acc[nt], 0, 0, 0);
    }
  }

  // ---- all waves dump partials; combine split across waves ----
#pragma unroll
  for (int nt = 0; nt < 4; ++nt)
#pragma unroll
    for (int r = 0; r < 4; ++r)
      o_buf[w][quad * 4 + r][nt * 16 + ln] = o_acc[nt][r];
#pragma unroll
  for (int r = 0; r < 4; ++r) l_buf[w][quad * 4 + r][ln] = l_part[r];
  __syncthreads();

#pragma unroll
  for (int rr = 0; rr < 2; ++rr) {
    const int row = w + rr * 8;
    float o = 0.f, lsum = 0.f;
#pragma unroll
    for (int ww = 0; ww < 8; ++ww) {
      o += o_buf[ww][row][lane];
      lsum += l_buf[ww][row][lane & 15];
    }
#pragma unroll
    for (int off = 1; off < 16; off <<= 1) lsum += __shfl_xor(lsum, off);
    out[(bt + qr0 + row) * HS_ + lane] = o / lsum;
  }
}

// ---------------------------------------------------------------------------
extern "C" void kernel_launch(void* const* d_in, const int* in_sizes, int n_in,
                              void* d_out, int out_size, void* d_ws,
                              size_t ws_size, hipStream_t stream) {
  (void)in_sizes; (void)n_in; (void)out_size; (void)ws_size;
  const float* xq = (const float*)d_in[0];   // fp32 in / fp32 out: proven R4
  const float* xkv = (const float*)d_in[1];
  const float* Wq = (const float*)d_in[2];
  const float* Wk = (const float*)d_in[3];
  const float* Wv = (const float*)d_in[4];
  float* out = (float*)d_out;

  char* ws = (char*)d_ws;
  bf16_t* q = (bf16_t*)ws;                              // 2 MB   [B*T][64]
  bf16_t* kk = (bf16_t*)(ws + (2u << 20));              // 2 MB   [B*T][64]
  bf16_t* vT = (bf16_t*)(ws + (4u << 20));              // 2.04MB [B][64][VSTRIDE]
  bf16_t* pq = (bf16_t*)(ws + (6656u << 10));           // 128 KB packed W @6.5MB
  bf16_t* pk = (bf16_t*)(ws + (6784u << 10));
  bf16_t* pv = (bf16_t*)(ws + (6912u << 10));

  repack_w<<<dim3(32, 3), 256, 0, stream>>>(Wq, Wk, Wv, pq, pk, pv);
  proj_mfma<<<dim3(256, 2), 256, 0, stream>>>(xq, xkv, pq, pk, pv, q, kk, vT);
  attn_mfma<<<dim3(1024), 512, 0, stream>>>(q, kk, vT, out);
}

// Round 6
// 197.342 us; speedup vs baseline: 1.1082x; 1.0042x over previous
//
#include <hip/hip_runtime.h>

typedef __bf16 bf16_t;
typedef __bf16 bf16x8 __attribute__((ext_vector_type(8)));
typedef float f32x4 __attribute__((ext_vector_type(4)));
typedef unsigned short u16x4 __attribute__((ext_vector_type(4)));

#define B_ 8
#define T_ 2048
#define C_ 1024
#define HS_ 64
#define VSTRIDE 2080  // vT row stride (T_+32): de-alias 4KB channel hotspot

#define MFMA __builtin_amdgcn_mfma_f32_16x16x32_bf16

__device__ __forceinline__ float fast_exp2(float x) {
#if __has_builtin(__builtin_amdgcn_exp2f)
  return __builtin_amdgcn_exp2f(x);
#else
  return exp2f(x);
#endif
}

// async 16B/lane global->LDS: PER-LANE gsrc, wave-uniform LDS base (+lane*16)
__device__ __forceinline__ void async_ld16(const void* gsrc, void* lds_dst) {
  __builtin_amdgcn_global_load_lds(
      (const __attribute__((address_space(1))) void*)gsrc,
      (__attribute__((address_space(3))) void*)lds_dst, 16, 0, 0);
}

// ---------------------------------------------------------------------------
// Kernel 1: repack W [1024][64] fp32 -> bf16 MFMA B-fragment order.
// Pack index: ((kc*4 + nt)*64 + lane)*8  =  W[kc*32 + quad*8 + j][nt*16 + ln]
// ---------------------------------------------------------------------------
__global__ __launch_bounds__(256) void repack_w(
    const float* __restrict__ Wq, const float* __restrict__ Wk,
    const float* __restrict__ Wv, bf16_t* __restrict__ pq,
    bf16_t* __restrict__ pk, bf16_t* __restrict__ pv) {
  const float* W = (blockIdx.y == 0) ? Wq : ((blockIdx.y == 1) ? Wk : Wv);
  bf16_t* P = (blockIdx.y == 0) ? pq : ((blockIdx.y == 1) ? pk : pv);
  int t = blockIdx.x * 256 + threadIdx.x;  // 0..8191
  int lane = t & 63, nt = (t >> 6) & 3, kc = t >> 8;
  int quad = lane >> 4, ln = lane & 15;
  bf16x8 v;
#pragma unroll
  for (int j = 0; j < 8; ++j)
    v[j] = (bf16_t)W[(kc * 32 + quad * 8 + j) * HS_ + nt * 16 + ln];
  *(bf16x8*)(P + (size_t)t * 8) = v;
}

// ---------------------------------------------------------------------------
// Kernel 2: MFMA projections — ROW-CHUNKED staging (R10, lane-addr fixed R11).
// R11 fix: R10 passed a LANE-UNIFORM global address to global_load_lds; the
// global side is per-lane (LDS side is uniform-base + lane*16), so all lanes
// fetched the same 16B -> garbage tiles (absmax 5.3). Source now + lane*4.
// Design (R10): chunk = 16 FULL rows = contiguous 64KB run (kills the 4KB-
// stride channel hotspot that capped column-chunks at ~1.4 TB/s). Full-K per
// chunk -> outputs complete per chunk; W-frags chunk-invariant, preloaded in
// VGPRs (vmcnt stream stays staging-only); 8 waves = (K-half kh) x (nt); kv
// waves do K and V MFMAs off one shared A-frag read; K-split partials
// combine via an 8KB LDS buffer on the pipeline's existing barriers; A-rows
// padded +16B (1028 f32) to rotate bank-quads per row (linear LDS dst, no
// swizzle needed); global stores deferred past the loop so counted vmcnt(8)
// stays exact. Grid (128,2) x 512 thr, 8 chunks/block, 1 block/CU.
// (R13: second resubmit — R11 never ran; container fail x2, then broker
// acquisition timeout. No hardware evidence yet for this version.)
// ---------------------------------------------------------------------------
__global__ __launch_bounds__(512, 2) void proj_mfma(
    const float* __restrict__ xq, const float* __restrict__ xkv,
    const bf16_t* __restrict__ pq, const bf16_t* __restrict__ pk,
    const bf16_t* __restrict__ pv, bf16_t* __restrict__ q,
    bf16_t* __restrict__ k, bf16_t* __restrict__ vT) {
  __shared__ float Xb[2][16][1028];      // 128.5 KB ping-pong: 16 full rows
  __shared__ float red[2][4][4][16][4];  // 8 KB: K-split partial tiles

  const bool is_kv = (blockIdx.y != 0);
  const float* x = is_kv ? xkv : xq;

  const int w = threadIdx.x >> 6, lane = threadIdx.x & 63;
  const int quad = lane >> 4, ln = lane & 15;
  const int kh = w >> 2, nt = w & 3;  // wave = (K-half, n-tile)

  // ---- B-fragment preload: K-half kh, cols nt*16..+16 (64/128 VGPR) ------
  bf16x8 bfr[32];
#pragma unroll
  for (int j = 0; j < 16; ++j) {
    const size_t idx = (((size_t)(kh * 16 + j) * 4 + nt) * 64 + lane) * 8;
    bfr[j * 2] = *(const bf16x8*)((is_kv ? pk : pq) + idx);
    if (is_kv) bfr[j * 2 + 1] = *(const bf16x8*)(pv + idx);
  }

  // ---- stage chunk c: 16 full rows, contiguous 64KB; 8 instrs/wave -------
  auto STAGE = [&](int c) {
    const size_t g = (size_t)blockIdx.x * 8 + c;
    const int buf = c & 1;
#pragma unroll
    for (int i = 0; i < 2; ++i) {
      const int r = w * 2 + i;  // wave w stages rows 2w, 2w+1 (8KB contig)
      const float* src = x + (g * 16 + r) * C_;
#pragma unroll
      for (int qt = 0; qt < 4; ++qt)
        async_ld16(src + qt * 256 + lane * 4, &Xb[buf][r][qt * 256]);
    }
  };

  // ---- compute chunk from LDS only; A-frag shared across K/V MFMAs -------
  auto COMPUTE = [&](int buf, f32x4& a0, f32x4& a1) {
    const char* rp = (const char*)&Xb[buf][ln][0];  // row pad 4112B: bank
    if (is_kv) {                                    // quad rotates with ln
#pragma unroll
      for (int j = 0; j < 16; ++j) {
        const int s0 = (kh * 16 + j) * 8 + quad * 2;  // 16B-slot index
        f32x4 xlo = *(const f32x4*)(rp + s0 * 16);
        f32x4 xhi = *(const f32x4*)(rp + s0 * 16 + 16);
        bf16x8 a;
#pragma unroll
        for (int jj = 0; jj < 4; ++jj) {
          a[jj] = (bf16_t)xlo[jj];
          a[4 + jj] = (bf16_t)xhi[jj];
        }
        a0 = MFMA(a, bfr[j * 2], a0, 0, 0, 0);
        a1 = MFMA(a, bfr[j * 2 + 1], a1, 0, 0, 0);
      }
    } else {
#pragma unroll
      for (int j = 0; j < 16; ++j) {
        const int s0 = (kh * 16 + j) * 8 + quad * 2;
        f32x4 xlo = *(const f32x4*)(rp + s0 * 16);
        f32x4 xhi = *(const f32x4*)(rp + s0 * 16 + 16);
        bf16x8 a;
#pragma unroll
        for (int jj = 0; jj < 4; ++jj) {
          a[jj] = (bf16_t)xlo[jj];
          a[4 + jj] = (bf16_t)xhi[jj];
        }
        a0 = MFMA(a, bfr[j * 2], a0, 0, 0, 0);
      }
    }
  };

  u16x4 ow0[8], ow1[8];

  // prologue: chunks 0,1 in flight; wait only chunk 0 (B preload is older,
  // so vmcnt(8) also retires it)
  STAGE(0);
  STAGE(1);
  asm volatile("s_waitcnt vmcnt(8)" ::: "memory");
  __builtin_amdgcn_s_barrier();
  __builtin_amdgcn_sched_barrier(0);

#pragma unroll
  for (int c = 0; c < 8; ++c) {
    f32x4 acc0 = (f32x4){0.f, 0.f, 0.f, 0.f};
    f32x4 acc1 = (f32x4){0.f, 0.f, 0.f, 0.f};
    COMPUTE(c & 1, acc0, acc1);
    if (kh == 1) {  // publish partial tiles
      *(f32x4*)&red[0][nt][quad][ln][0] = acc0;
      if (is_kv) *(f32x4*)&red[1][nt][quad][ln][0] = acc1;
    }
    asm volatile("s_waitcnt lgkmcnt(0)" ::: "memory");  // Xb reads + red wr
    __builtin_amdgcn_s_barrier();
    __builtin_amdgcn_sched_barrier(0);
    if (kh == 0) {  // combine K-halves, pack to regs (stores deferred)
      acc0 += *(const f32x4*)&red[0][nt][quad][ln][0];
      if (is_kv) acc1 += *(const f32x4*)&red[1][nt][quad][ln][0];
#pragma unroll
      for (int r = 0; r < 4; ++r) {
        bf16_t h0 = (bf16_t)acc0[r];
        ow0[c][r] = *(unsigned short*)&h0;
        bf16_t h1 = (bf16_t)acc1[r];
        ow1[c][r] = *(unsigned short*)&h1;
      }
    }
    if (c == 7) break;
    if (c < 6) {
      STAGE(c + 2);  // overwrite just-freed buffer
      asm volatile("s_waitcnt vmcnt(8)" ::: "memory");  // c+1 landed
    } else {
      asm volatile("s_waitcnt vmcnt(0)" ::: "memory");  // drain chunk 7
    }
    __builtin_amdgcn_s_barrier();
    __builtin_amdgcn_sched_barrier(0);
  }

  // ---- epilogue stores (kh==0 waves hold the combined tiles) -------------
  if (kh != 0) return;
  if (!is_kv) {
#pragma unroll
    for (int c = 0; c < 8; ++c) {
      const int R0 = (blockIdx.x * 8 + c) * 16;
#pragma unroll
      for (int r = 0; r < 4; ++r)
        *((unsigned short*)q + (size_t)(R0 + quad * 4 + r) * HS_ + nt * 16 +
          ln) = ow0[c][r];
    }
  } else {
#pragma unroll
    for (int c = 0; c < 8; ++c) {
      const int R0 = (blockIdx.x * 8 + c) * 16;
#pragma unroll
      for (int r = 0; r < 4; ++r)
        *((unsigned short*)k + (size_t)(R0 + quad * 4 + r) * HS_ + nt * 16 +
          ln) = ow0[c][r];
      const int bb = R0 >> 11;
      const int t0 = (R0 & (T_ - 1)) + quad * 4;
      *(u16x4*)((unsigned short*)vT +
                ((size_t)(bb * HS_ + nt * 16 + ln)) * VSTRIDE + t0) = ow1[c];
    }
  }
}

// ---------------------------------------------------------------------------
// Kernel 3: causal flash attention, KV-split x8, parallel epilogue.
// (unchanged from R9: reg-pipelined bk/bv, batch->XCD affinity, heavy-first)
// ---------------------------------------------------------------------------
__global__ __launch_bounds__(512, 4) void attn_mfma(
    const bf16_t* __restrict__ q, const bf16_t* __restrict__ k,
    const bf16_t* __restrict__ vT, float* __restrict__ out) {
  __shared__ bf16_t p_lds[8][16][80];   // 20 KB: per-wave P transpose
  __shared__ float o_buf[8][16][66];    // 33 KB: all 8 waves' partial O
  __shared__ float l_buf[8][16][17];    //  8.7 KB: per-lane l partials

  const int b = blockIdx.x & 7;            // batch == XCD (round-robin %8)
  const int gq = 127 - (blockIdx.x >> 3);  // heavy q-groups launch first
  const int w = threadIdx.x >> 6, lane = threadIdx.x & 63;
  const int quad = lane >> 4, ln = lane & 15;
  const int qr0 = gq * 16;
  const size_t bt = (size_t)b * T_;
  const int td = gq >> 2;               // diagonal 64-key tile index

  bf16x8 aq[2];
#pragma unroll
  for (int hc = 0; hc < 2; ++hc)
    aq[hc] = *(const bf16x8*)(q + (bt + qr0 + ln) * HS_ + hc * 32 + quad * 8);

  f32x4 o_acc[4];
  float l_part[4] = {0.f, 0.f, 0.f, 0.f};
#pragma unroll
  for (int nt = 0; nt < 4; ++nt) o_acc[nt] = (f32x4){0.f, 0.f, 0.f, 0.f};
  const float scl = 0.03125f * 1.44269504088896340736f;  // C^-0.5 * log2(e)

  bf16x8 bk[8], bv[8];
  int t = w;
  if (t <= td) {  // prologue K-frag load for first tile
#pragma unroll
    for (int hc = 0; hc < 2; ++hc)
#pragma unroll
      for (int nt = 0; nt < 4; ++nt)
        bk[hc * 4 + nt] = *(const bf16x8*)(k + (bt + t * 64 + nt * 16 + ln) * HS_ +
                                           hc * 32 + quad * 8);
  }

  for (; t <= td; t += 8) {
    const int kr0 = t * 64;

    // ---- V-frag loads for THIS tile: independent of S, issue first ----
#pragma unroll
    for (int kc = 0; kc < 2; ++kc)
#pragma unroll
      for (int nt = 0; nt < 4; ++nt)
        bv[kc * 4 + nt] = *(const bf16x8*)(vT +
                                           ((size_t)(b * HS_ + nt * 16 + ln)) * VSTRIDE +
                                           kr0 + kc * 32 + quad * 8);

    // ---- S = Q K^T (16 q-rows x 64 keys), consumes bk ----
    f32x4 s[4];
#pragma unroll
    for (int nt = 0; nt < 4; ++nt) s[nt] = (f32x4){0.f, 0.f, 0.f, 0.f};
#pragma unroll
    for (int hc = 0; hc < 2; ++hc)
#pragma unroll
      for (int nt = 0; nt < 4; ++nt)
        s[nt] = MFMA(aq[hc], bk[hc * 4 + nt], s[nt], 0, 0, 0);

    // ---- prefetch next tile's K-frags (bk free after S-MFMA issue) ----
    if (t + 8 <= td) {
#pragma unroll
      for (int hc = 0; hc < 2; ++hc)
#pragma unroll
        for (int nt = 0; nt < 4; ++nt)
          bk[hc * 4 + nt] = *(const bf16x8*)(k +
                                             (bt + (t + 8) * 64 + nt * 16 + ln) * HS_ +
                                             hc * 32 + quad * 8);
    }

    // ---- p = exp(s/32), mask diagonal tile, accumulate l, stage P ----
    const bool diag = (t == td);
#pragma unroll
    for (int nt = 0; nt < 4; ++nt)
#pragma unroll
      for (int r = 0; r < 4; ++r) {
        float e = fast_exp2(s[nt][r] * scl);
        if (diag && (kr0 + nt * 16 + ln > qr0 + quad * 4 + r)) e = 0.f;
        l_part[r] += e;
        p_lds[w][quad * 4 + r][nt * 16 + ln] = (bf16_t)e;
      }

    // ---- O += P V (per-wave LDS slice; same-wave DS ordering) ----
#pragma unroll
    for (int kc = 0; kc < 2; ++kc) {
      bf16x8 ap = *(const bf16x8*)&p_lds[w][ln][kc * 32 + quad * 8];
#pragma unroll
      for (int nt = 0; nt < 4; ++nt)
        o_acc[nt] = MFMA(ap, bv[kc * 4 + nt], o_acc[nt], 0, 0, 0);
    }
  }

  // ---- all waves dump partials; combine split across waves ----
#pragma unroll
  for (int nt = 0; nt < 4; ++nt)
#pragma unroll
    for (int r = 0; r < 4; ++r)
      o_buf[w][quad * 4 + r][nt * 16 + ln] = o_acc[nt][r];
#pragma unroll
  for (int r = 0; r < 4; ++r) l_buf[w][quad * 4 + r][ln] = l_part[r];
  __syncthreads();

#pragma unroll
  for (int rr = 0; rr < 2; ++rr) {
    const int row = w + rr * 8;
    float o = 0.f, lsum = 0.f;
#pragma unroll
    for (int ww = 0; ww < 8; ++ww) {
      o += o_buf[ww][row][lane];
      lsum += l_buf[ww][row][lane & 15];
    }
#pragma unroll
    for (int off = 1; off < 16; off <<= 1) lsum += __shfl_xor(lsum, off);
    out[(bt + qr0 + row) * HS_ + lane] = o / lsum;
  }
}

// ---------------------------------------------------------------------------
extern "C" void kernel_launch(void* const* d_in, const int* in_sizes, int n_in,
                              void* d_out, int out_size, void* d_ws,
                              size_t ws_size, hipStream_t stream) {
  (void)in_sizes; (void)n_in; (void)out_size; (void)ws_size;
  const float* xq = (const float*)d_in[0];   // fp32 in / fp32 out: proven R4
  const float* xkv = (const float*)d_in[1];
  const float* Wq = (const float*)d_in[2];
  const float* Wk = (const float*)d_in[3];
  const float* Wv = (const float*)d_in[4];
  float* out = (float*)d_out;

  char* ws = (char*)d_ws;
  bf16_t* q = (bf16_t*)ws;                              // 2 MB   [B*T][64]
  bf16_t* kk = (bf16_t*)(ws + (2u << 20));              // 2 MB   [B*T][64]
  bf16_t* vT = (bf16_t*)(ws + (4u << 20));              // 2.04MB [B][64][VSTRIDE]
  bf16_t* pq = (bf16_t*)(ws + (6656u << 10));           // 128 KB packed W @6.5MB
  bf16_t* pk = (bf16_t*)(ws + (6784u << 10));
  bf16_t* pv = (bf16_t*)(ws + (6912u << 10));

  repack_w<<<dim3(32, 3), 256, 0, stream>>>(Wq, Wk, Wv, pq, pk, pv);
  proj_mfma<<<dim3(128, 2), 512, 0, stream>>>(xq, xkv, pq, pk, pv, q, kk, vT);
  attn_mfma<<<dim3(1024), 512, 0, stream>>>(q, kk, vT, out);
}

// Round 7
// 194.653 us; speedup vs baseline: 1.1235x; 1.0138x over previous
//
#include <hip/hip_runtime.h>

typedef __bf16 bf16_t;
typedef __bf16 bf16x8 __attribute__((ext_vector_type(8)));
typedef float f32x4 __attribute__((ext_vector_type(4)));
typedef unsigned short u16x4 __attribute__((ext_vector_type(4)));

#define B_ 8
#define T_ 2048
#define C_ 1024
#define HS_ 64
#define VSTRIDE 2080  // vT row stride (T_+32): de-alias 4KB channel hotspot

#define MFMA __builtin_amdgcn_mfma_f32_16x16x32_bf16

__device__ __forceinline__ float fast_exp2(float x) {
#if __has_builtin(__builtin_amdgcn_exp2f)
  return __builtin_amdgcn_exp2f(x);
#else
  return exp2f(x);
#endif
}

// ---------------------------------------------------------------------------
// Kernel 1: repack W [1024][64] fp32 -> bf16 MFMA B-fragment order.
// Pack index: ((kc*4 + nt)*64 + lane)*8  =  W[kc*32 + quad*8 + j][nt*16 + ln]
// ---------------------------------------------------------------------------
__global__ __launch_bounds__(256) void repack_w(
    const float* __restrict__ Wq, const float* __restrict__ Wk,
    const float* __restrict__ Wv, bf16_t* __restrict__ pq,
    bf16_t* __restrict__ pk, bf16_t* __restrict__ pv) {
  const float* W = (blockIdx.y == 0) ? Wq : ((blockIdx.y == 1) ? Wk : Wv);
  bf16_t* P = (blockIdx.y == 0) ? pq : ((blockIdx.y == 1) ? pk : pv);
  int t = blockIdx.x * 256 + threadIdx.x;  // 0..8191
  int lane = t & 63, nt = (t >> 6) & 3, kc = t >> 8;
  int quad = lane >> 4, ln = lane & 15;
  bf16x8 v;
#pragma unroll
  for (int j = 0; j < 8; ++j)
    v[j] = (bf16_t)W[(kc * 32 + quad * 8 + j) * HS_ + nt * 16 + ln];
  *(bf16x8*)(P + (size_t)t * 8) = v;
}

// ---------------------------------------------------------------------------
// Kernel 2: MFMA projections — ROW-CHUNKED, REG-STAGED (R14).
// R14 diagnosis: R11 measured 52us / 1.4 TB/s — identical to the column-
// chunked R8 AND the pre-session direct-load variant. Per-chunk arithmetic:
// 64KB/CU staged in 6.5us = ~10 GB/s/CU = one 1KB global_load_lds retired
// per ~250cy per CU — the async global->LDS path behaves as a SERIAL queue
// at ~L2 latency per instruction (no overlap across 64 outstanding loads).
// Compute is 0.7us/chunk; HBM/LDS/banks all >=10x off the path. The only
// component shared by every ~1.4 TB/s variant is global_load_lds itself.
// Fix under test: reg-staging (global_load_dwordx4 -> VGPR -> ds_write_b128,
// the m13-proven 6.3 TB/s load pattern), SAME chunk geometry, SAME LDS
// layout (+16B row pad), SAME two-barrier skeleton. ISSUE(c+2) pinned early
// by sched_barrier(0); vmcnt(0) before the WRITE is exact (only chunk c+1's
// 8 loads outstanding; stores deferred to epilogue). Issue->wait gap spans
// a full compute phase so L2/HBM latency stays hidden.
// Grid (128,2) x 512 thr, 8 chunks/block, 1 block/CU (136.5 KB LDS).
// ---------------------------------------------------------------------------
__global__ __launch_bounds__(512, 2) void proj_mfma(
    const float* __restrict__ xq, const float* __restrict__ xkv,
    const bf16_t* __restrict__ pq, const bf16_t* __restrict__ pk,
    const bf16_t* __restrict__ pv, bf16_t* __restrict__ q,
    bf16_t* __restrict__ k, bf16_t* __restrict__ vT) {
  __shared__ float Xb[2][16][1028];      // 128.5 KB ping-pong: 16 full rows
  __shared__ float red[2][4][4][16][4];  // 8 KB: K-split partial tiles

  const bool is_kv = (blockIdx.y != 0);
  const float* x = is_kv ? xkv : xq;

  const int w = threadIdx.x >> 6, lane = threadIdx.x & 63;
  const int quad = lane >> 4, ln = lane & 15;
  const int kh = w >> 2, nt = w & 3;  // wave = (K-half, n-tile)

  // ---- B-fragment preload: K-half kh, cols nt*16..+16 (64/128 VGPR) ------
  bf16x8 bfr[32];
#pragma unroll
  for (int j = 0; j < 16; ++j) {
    const size_t idx = (((size_t)(kh * 16 + j) * 4 + nt) * 64 + lane) * 8;
    bfr[j * 2] = *(const bf16x8*)((is_kv ? pk : pq) + idx);
    if (is_kv) bfr[j * 2 + 1] = *(const bf16x8*)(pv + idx);
  }

  // ---- reg-staging: wave w owns rows {2w, 2w+1} of each 16-row chunk -----
  f32x4 R[8];  // 8 x 16B/lane = wave covers 8KB (2 rows x 4KB)
  auto ISSUE = [&](int c) {  // issue 8 global dwordx4 loads -> R
    const size_t g = (size_t)blockIdx.x * 8 + c;
#pragma unroll
    for (int i = 0; i < 8; ++i) {
      const int r = w * 2 + (i >> 2);
      R[i] = *(const f32x4*)(x + (g * 16 + r) * C_ + (i & 3) * 256 + lane * 4);
    }
    __builtin_amdgcn_sched_barrier(0);  // pin issue point (no sinking)
  };
  auto WRITE = [&](int c) {  // R -> LDS (per-lane addr; contiguous 16B/lane)
    const int buf = c & 1;
#pragma unroll
    for (int i = 0; i < 8; ++i) {
      const int r = w * 2 + (i >> 2);
      *(f32x4*)&Xb[buf][r][(i & 3) * 256 + lane * 4] = R[i];
    }
  };

  // ---- compute chunk from LDS only; A-frag shared across K/V MFMAs -------
  auto COMPUTE = [&](int buf, f32x4& a0, f32x4& a1) {
    const char* rp = (const char*)&Xb[buf][ln][0];  // row pad 4112B: bank
    if (is_kv) {                                    // quad rotates with ln
#pragma unroll
      for (int j = 0; j < 16; ++j) {
        const int s0 = (kh * 16 + j) * 8 + quad * 2;  // 16B-slot index
        f32x4 xlo = *(const f32x4*)(rp + s0 * 16);
        f32x4 xhi = *(const f32x4*)(rp + s0 * 16 + 16);
        bf16x8 a;
#pragma unroll
        for (int jj = 0; jj < 4; ++jj) {
          a[jj] = (bf16_t)xlo[jj];
          a[4 + jj] = (bf16_t)xhi[jj];
        }
        a0 = MFMA(a, bfr[j * 2], a0, 0, 0, 0);
        a1 = MFMA(a, bfr[j * 2 + 1], a1, 0, 0, 0);
      }
    } else {
#pragma unroll
      for (int j = 0; j < 16; ++j) {
        const int s0 = (kh * 16 + j) * 8 + quad * 2;
        f32x4 xlo = *(const f32x4*)(rp + s0 * 16);
        f32x4 xhi = *(const f32x4*)(rp + s0 * 16 + 16);
        bf16x8 a;
#pragma unroll
        for (int jj = 0; jj < 4; ++jj) {
          a[jj] = (bf16_t)xlo[jj];
          a[4 + jj] = (bf16_t)xhi[jj];
        }
        a0 = MFMA(a, bfr[j * 2], a0, 0, 0, 0);
      }
    }
  };

  u16x4 ow0[8], ow1[8];

  // prologue: load+write chunk 0, leave chunk 1 in R
  ISSUE(0);
  asm volatile("s_waitcnt vmcnt(0)" ::: "memory");  // also retires bfr
  WRITE(0);
  ISSUE(1);
  asm volatile("s_waitcnt lgkmcnt(0)" ::: "memory");
  __builtin_amdgcn_s_barrier();
  __builtin_amdgcn_sched_barrier(0);

#pragma unroll
  for (int c = 0; c < 8; ++c) {
    f32x4 acc0 = (f32x4){0.f, 0.f, 0.f, 0.f};
    f32x4 acc1 = (f32x4){0.f, 0.f, 0.f, 0.f};
    COMPUTE(c & 1, acc0, acc1);
    if (kh == 1) {  // publish partial tiles
      *(f32x4*)&red[0][nt][quad][ln][0] = acc0;
      if (is_kv) *(f32x4*)&red[1][nt][quad][ln][0] = acc1;
    }
    asm volatile("s_waitcnt lgkmcnt(0)" ::: "memory");  // Xb reads + red wr
    __builtin_amdgcn_s_barrier();                       // buf free, red pub
    __builtin_amdgcn_sched_barrier(0);
    if (kh == 0) {  // combine K-halves, pack to regs (stores deferred)
      acc0 += *(const f32x4*)&red[0][nt][quad][ln][0];
      if (is_kv) acc1 += *(const f32x4*)&red[1][nt][quad][ln][0];
#pragma unroll
      for (int r = 0; r < 4; ++r) {
        bf16_t h0 = (bf16_t)acc0[r];
        ow0[c][r] = *(unsigned short*)&h0;
        bf16_t h1 = (bf16_t)acc1[r];
        ow1[c][r] = *(unsigned short*)&h1;
      }
    }
    if (c == 7) break;
    asm volatile("s_waitcnt vmcnt(0)" ::: "memory");  // chunk c+1 in R
    WRITE(c + 1);                                     // into buf[(c+1)&1]
    if (c + 2 < 8) ISSUE(c + 2);                      // refill R
    asm volatile("s_waitcnt lgkmcnt(0)" ::: "memory");  // my writes done
    __builtin_amdgcn_s_barrier();                       // buf c+1 visible
    __builtin_amdgcn_sched_barrier(0);
  }

  // ---- epilogue stores (kh==0 waves hold the combined tiles) -------------
  if (kh != 0) return;
  if (!is_kv) {
#pragma unroll
    for (int c = 0; c < 8; ++c) {
      const int R0 = (blockIdx.x * 8 + c) * 16;
#pragma unroll
      for (int r = 0; r < 4; ++r)
        *((unsigned short*)q + (size_t)(R0 + quad * 4 + r) * HS_ + nt * 16 +
          ln) = ow0[c][r];
    }
  } else {
#pragma unroll
    for (int c = 0; c < 8; ++c) {
      const int R0 = (blockIdx.x * 8 + c) * 16;
#pragma unroll
      for (int r = 0; r < 4; ++r)
        *((unsigned short*)k + (size_t)(R0 + quad * 4 + r) * HS_ + nt * 16 +
          ln) = ow0[c][r];
      const int bb = R0 >> 11;
      const int t0 = (R0 & (T_ - 1)) + quad * 4;
      *(u16x4*)((unsigned short*)vT +
                ((size_t)(bb * HS_ + nt * 16 + ln)) * VSTRIDE + t0) = ow1[c];
    }
  }
}

// ---------------------------------------------------------------------------
// Kernel 3: causal flash attention, KV-split x8, parallel epilogue.
// R14: R1's bk/bv software pipeline was silently DEFEATED by the scheduler
// (VGPR_Count=56 < the >=64 regs bk[8]+bv[8] require -> compiler sank the
// prefetches back to their uses). Pin issue points with sched_barrier(0)
// after the prologue-load, bv-load, and bk-prefetch blocks. No other change.
// ---------------------------------------------------------------------------
__global__ __launch_bounds__(512, 4) void attn_mfma(
    const bf16_t* __restrict__ q, const bf16_t* __restrict__ k,
    const bf16_t* __restrict__ vT, float* __restrict__ out) {
  __shared__ bf16_t p_lds[8][16][80];   // 20 KB: per-wave P transpose
  __shared__ float o_buf[8][16][66];    // 33 KB: all 8 waves' partial O
  __shared__ float l_buf[8][16][17];    //  8.7 KB: per-lane l partials

  const int b = blockIdx.x & 7;            // batch == XCD (round-robin %8)
  const int gq = 127 - (blockIdx.x >> 3);  // heavy q-groups launch first
  const int w = threadIdx.x >> 6, lane = threadIdx.x & 63;
  const int quad = lane >> 4, ln = lane & 15;
  const int qr0 = gq * 16;
  const size_t bt = (size_t)b * T_;
  const int td = gq >> 2;               // diagonal 64-key tile index

  bf16x8 aq[2];
#pragma unroll
  for (int hc = 0; hc < 2; ++hc)
    aq[hc] = *(const bf16x8*)(q + (bt + qr0 + ln) * HS_ + hc * 32 + quad * 8);

  f32x4 o_acc[4];
  float l_part[4] = {0.f, 0.f, 0.f, 0.f};
#pragma unroll
  for (int nt = 0; nt < 4; ++nt) o_acc[nt] = (f32x4){0.f, 0.f, 0.f, 0.f};
  const float scl = 0.03125f * 1.44269504088896340736f;  // C^-0.5 * log2(e)

  bf16x8 bk[8], bv[8];
  int t = w;
  if (t <= td) {  // prologue K-frag load for first tile
#pragma unroll
    for (int hc = 0; hc < 2; ++hc)
#pragma unroll
      for (int nt = 0; nt < 4; ++nt)
        bk[hc * 4 + nt] = *(const bf16x8*)(k + (bt + t * 64 + nt * 16 + ln) * HS_ +
                                           hc * 32 + quad * 8);
    __builtin_amdgcn_sched_barrier(0);  // pin prologue issue
  }

  for (; t <= td; t += 8) {
    const int kr0 = t * 64;

    // ---- V-frag loads for THIS tile: independent of S, issue first ----
#pragma unroll
    for (int kc = 0; kc < 2; ++kc)
#pragma unroll
      for (int nt = 0; nt < 4; ++nt)
        bv[kc * 4 + nt] = *(const bf16x8*)(vT +
                                           ((size_t)(b * HS_ + nt * 16 + ln)) * VSTRIDE +
                                           kr0 + kc * 32 + quad * 8);
    __builtin_amdgcn_sched_barrier(0);  // pin bv issue before S-MFMAs

    // ---- S = Q K^T (16 q-rows x 64 keys), consumes bk ----
    f32x4 s[4];
#pragma unroll
    for (int nt = 0; nt < 4; ++nt) s[nt] = (f32x4){0.f, 0.f, 0.f, 0.f};
#pragma unroll
    for (int hc = 0; hc < 2; ++hc)
#pragma unroll
      for (int nt = 0; nt < 4; ++nt)
        s[nt] = MFMA(aq[hc], bk[hc * 4 + nt], s[nt], 0, 0, 0);

    // ---- prefetch next tile's K-frags (bk free after S-MFMA issue) ----
    if (t + 8 <= td) {
#pragma unroll
      for (int hc = 0; hc < 2; ++hc)
#pragma unroll
        for (int nt = 0; nt < 4; ++nt)
          bk[hc * 4 + nt] = *(const bf16x8*)(k +
                                             (bt + (t + 8) * 64 + nt * 16 + ln) * HS_ +
                                             hc * 32 + quad * 8);
      __builtin_amdgcn_sched_barrier(0);  // pin bk prefetch issue
    }

    // ---- p = exp(s/32), mask diagonal tile, accumulate l, stage P ----
    const bool diag = (t == td);
#pragma unroll
    for (int nt = 0; nt < 4; ++nt)
#pragma unroll
      for (int r = 0; r < 4; ++r) {
        float e = fast_exp2(s[nt][r] * scl);
        if (diag && (kr0 + nt * 16 + ln > qr0 + quad * 4 + r)) e = 0.f;
        l_part[r] += e;
        p_lds[w][quad * 4 + r][nt * 16 + ln] = (bf16_t)e;
      }

    // ---- O += P V (per-wave LDS slice; same-wave DS ordering) ----
#pragma unroll
    for (int kc = 0; kc < 2; ++kc) {
      bf16x8 ap = *(const bf16x8*)&p_lds[w][ln][kc * 32 + quad * 8];
#pragma unroll
      for (int nt = 0; nt < 4; ++nt)
        o_acc[nt] = MFMA(ap, bv[kc * 4 + nt], o_acc[nt], 0, 0, 0);
    }
  }

  // ---- all waves dump partials; combine split across waves ----
#pragma unroll
  for (int nt = 0; nt < 4; ++nt)
#pragma unroll
    for (int r = 0; r < 4; ++r)
      o_buf[w][quad * 4 + r][nt * 16 + ln] = o_acc[nt][r];
#pragma unroll
  for (int r = 0; r < 4; ++r) l_buf[w][quad * 4 + r][ln] = l_part[r];
  __syncthreads();

#pragma unroll
  for (int rr = 0; rr < 2; ++rr) {
    const int row = w + rr * 8;
    float o = 0.f, lsum = 0.f;
#pragma unroll
    for (int ww = 0; ww < 8; ++ww) {
      o += o_buf[ww][row][lane];
      lsum += l_buf[ww][row][lane & 15];
    }
#pragma unroll
    for (int off = 1; off < 16; off <<= 1) lsum += __shfl_xor(lsum, off);
    out[(bt + qr0 + row) * HS_ + lane] = o / lsum;
  }
}

// ---------------------------------------------------------------------------
extern "C" void kernel_launch(void* const* d_in, const int* in_sizes, int n_in,
                              void* d_out, int out_size, void* d_ws,
                              size_t ws_size, hipStream_t stream) {
  (void)in_sizes; (void)n_in; (void)out_size; (void)ws_size;
  const float* xq = (const float*)d_in[0];   // fp32 in / fp32 out: proven R4
  const float* xkv = (const float*)d_in[1];
  const float* Wq = (const float*)d_in[2];
  const float* Wk = (const float*)d_in[3];
  const float* Wv = (const float*)d_in[4];
  float* out = (float*)d_out;

  char* ws = (char*)d_ws;
  bf16_t* q = (bf16_t*)ws;                              // 2 MB   [B*T][64]
  bf16_t* kk = (bf16_t*)(ws + (2u << 20));              // 2 MB   [B*T][64]
  bf16_t* vT = (bf16_t*)(ws + (4u << 20));              // 2.04MB [B][64][VSTRIDE]
  bf16_t* pq = (bf16_t*)(ws + (6656u << 10));           // 128 KB packed W @6.5MB
  bf16_t* pk = (bf16_t*)(ws + (6784u << 10));
  bf16_t* pv = (bf16_t*)(ws + (6912u << 10));

  repack_w<<<dim3(32, 3), 256, 0, stream>>>(Wq, Wk, Wv, pq, pk, pv);
  proj_mfma<<<dim3(128, 2), 512, 0, stream>>>(xq, xkv, pq, pk, pv, q, kk, vT);
  attn_mfma<<<dim3(1024), 512, 0, stream>>>(q, kk, vT, out);
}